// Round 1
// baseline (382.685 us; speedup 1.0000x reference)
//
#include <hip/hip_runtime.h>
#include <hip/hip_bf16.h>

#define D 1024
#define TEMP_INV (1.0f / 0.92f)
#define EPS 1e-6f

typedef __bf16 bf16x4_t __attribute__((ext_vector_type(4)));
typedef __bf16 bf16x8_t __attribute__((ext_vector_type(8)));
typedef float f32x4_t __attribute__((ext_vector_type(4)));

typedef __attribute__((address_space(3))) void as3_void;
typedef const __attribute__((address_space(1))) void as1_void_c;

__device__ __forceinline__ void async_copy16(const __bf16* g, __bf16* l) {
    __builtin_amdgcn_global_load_lds((as1_void_c*)g, (as3_void*)l, 16, 0, 0);
}

// ---------------------------------------------------------------------------
// Kernel 1: convert Q,Neg to bf16; compute qn, nn, s1=exp(pos_sim/T); zero rowsum
// One block per row. 256 threads x float4 = 1024 elements.
// ---------------------------------------------------------------------------
__global__ __launch_bounds__(256) void prep_kernel(
    const float* __restrict__ q, const float* __restrict__ p,
    const float* __restrict__ neg,
    __bf16* __restrict__ Qb, __bf16* __restrict__ Nb,
    float* __restrict__ qn, float* __restrict__ nn,
    float* __restrict__ s1, float* __restrict__ rowsum, int B)
{
    __shared__ float red[12];
    const int row = blockIdx.x;
    const int tid = threadIdx.x;

    if (row < B) {
        const float4 qv = ((const float4*)(q + (size_t)row * D))[tid];
        const float4 pv = ((const float4*)(p + (size_t)row * D))[tid];
        bf16x4_t o;
        o[0] = (__bf16)qv.x; o[1] = (__bf16)qv.y; o[2] = (__bf16)qv.z; o[3] = (__bf16)qv.w;
        ((bf16x4_t*)(Qb + (size_t)row * D))[tid] = o;

        float qq = qv.x*qv.x + qv.y*qv.y + qv.z*qv.z + qv.w*qv.w;
        float pp = pv.x*pv.x + pv.y*pv.y + pv.z*pv.z + pv.w*pv.w;
        float qp = qv.x*pv.x + qv.y*pv.y + qv.z*pv.z + qv.w*pv.w;
        #pragma unroll
        for (int off = 32; off > 0; off >>= 1) {
            qq += __shfl_down(qq, off, 64);
            pp += __shfl_down(pp, off, 64);
            qp += __shfl_down(qp, off, 64);
        }
        const int w = tid >> 6;
        if ((tid & 63) == 0) { red[w] = qq; red[4 + w] = pp; red[8 + w] = qp; }
        __syncthreads();
        if (tid == 0) {
            float QQ = red[0] + red[1] + red[2] + red[3];
            float PP = red[4] + red[5] + red[6] + red[7];
            float QP = red[8] + red[9] + red[10] + red[11];
            float qnv = sqrtf(QQ);
            qn[row] = qnv;
            float den = fmaxf(qnv * sqrtf(PP), EPS);
            s1[row] = expf((QP / den) * TEMP_INV);
            rowsum[row] = 0.0f;
        }
    } else {
        const int r2 = row - B;
        const float4 nv = ((const float4*)(neg + (size_t)r2 * D))[tid];
        bf16x4_t o;
        o[0] = (__bf16)nv.x; o[1] = (__bf16)nv.y; o[2] = (__bf16)nv.z; o[3] = (__bf16)nv.w;
        ((bf16x4_t*)(Nb + (size_t)r2 * D))[tid] = o;

        float ss = nv.x*nv.x + nv.y*nv.y + nv.z*nv.z + nv.w*nv.w;
        #pragma unroll
        for (int off = 32; off > 0; off >>= 1) ss += __shfl_down(ss, off, 64);
        const int w = tid >> 6;
        if ((tid & 63) == 0) red[w] = ss;
        __syncthreads();
        if (tid == 0) nn[r2] = sqrtf(red[0] + red[1] + red[2] + red[3]);
    }
}

// ---------------------------------------------------------------------------
// Kernel 2: fused C = Qb * Nb^T (bf16 MFMA), epilogue exp + row-sum.
// 128x128 tile, BK=64, 256 threads = 4 waves in 2x2; each wave 64x64 via
// 4x4 grid of 16x16x32 MFMA fragments.
// ---------------------------------------------------------------------------
__global__ __launch_bounds__(256) void gemm_exp_rowsum(
    const __bf16* __restrict__ Qb, const __bf16* __restrict__ Nb,
    const float* __restrict__ qn, const float* __restrict__ nn,
    float* __restrict__ rowsum)
{
    __shared__ __bf16 As[128 * 64];
    __shared__ __bf16 Bs[128 * 64];

    const int tid = threadIdx.x;
    const int i0 = blockIdx.y * 128;   // Q rows
    const int j0 = blockIdx.x * 128;   // Neg rows

    const int lane = tid & 63;
    const int wid  = tid >> 6;
    const int wm   = wid & 1;          // wave row (2x2 wave grid)
    const int wn   = wid >> 1;         // wave col
    const int quad = lane >> 4;
    const int lc   = lane & 15;

    f32x4_t acc[4][4];
    #pragma unroll
    for (int mi = 0; mi < 4; ++mi)
        #pragma unroll
        for (int ni = 0; ni < 4; ++ni)
            acc[mi][ni] = (f32x4_t){0.f, 0.f, 0.f, 0.f};

    // staging: thread t copies 16B; row-in-chunk = t>>3, k-col = (t&7)*8,
    // chunk c covers rows c*32..c*32+31. LDS dest = base + tid*16B (wave-
    // uniform base + lane*16 as required by global_load_lds).
    const int tr = tid >> 3;
    const int kc = (tid & 7) * 8;
    const __bf16* ga = Qb + (size_t)(i0 + tr) * D + kc;
    const __bf16* gb = Nb + (size_t)(j0 + tr) * D + kc;
    __bf16* la = As + tid * 8;
    __bf16* lb = Bs + tid * 8;

    // LDS read bases: A row = wm*64 + mi*16 + lc, k = ks*32 + quad*8
    const __bf16* Abase = As + (size_t)(wm * 64 + lc) * 64 + quad * 8;
    const __bf16* Bbase = Bs + (size_t)(wn * 64 + lc) * 64 + quad * 8;

    for (int kt = 0; kt < D; kt += 64) {
        __syncthreads();   // protect LDS from overwrite while others read
        #pragma unroll
        for (int c = 0; c < 4; ++c) {
            async_copy16(ga + kt + c * (32 * D), la + c * 2048);
            async_copy16(gb + kt + c * (32 * D), lb + c * 2048);
        }
        __syncthreads();   // compiler drains vmcnt(0) before s_barrier

        #pragma unroll
        for (int ks = 0; ks < 2; ++ks) {
            bf16x8_t af[4], bf[4];
            #pragma unroll
            for (int mi = 0; mi < 4; ++mi)
                af[mi] = *(const bf16x8_t*)(Abase + mi * (16 * 64) + ks * 32);
            #pragma unroll
            for (int ni = 0; ni < 4; ++ni)
                bf[ni] = *(const bf16x8_t*)(Bbase + ni * (16 * 64) + ks * 32);
            #pragma unroll
            for (int mi = 0; mi < 4; ++mi)
                #pragma unroll
                for (int ni = 0; ni < 4; ++ni)
                    acc[mi][ni] = __builtin_amdgcn_mfma_f32_16x16x32_bf16(
                        af[mi], bf[ni], acc[mi][ni], 0, 0, 0);
        }
    }

    // Epilogue: e = exp(c / (T * max(qn_i * nn_j, eps))), row-reduce, atomicAdd.
    // C/D layout (16x16x32): col = lane&15, row = quad*4 + reg.
    float nnl[4];
    #pragma unroll
    for (int ni = 0; ni < 4; ++ni)
        nnl[ni] = nn[j0 + wn * 64 + ni * 16 + lc];

    #pragma unroll
    for (int mi = 0; mi < 4; ++mi) {
        const int rbase = i0 + wm * 64 + mi * 16 + quad * 4;
        const float4 qv = *(const float4*)&qn[rbase];
        float qa[4] = {qv.x, qv.y, qv.z, qv.w};
        float rs[4] = {0.f, 0.f, 0.f, 0.f};
        #pragma unroll
        for (int ni = 0; ni < 4; ++ni) {
            #pragma unroll
            for (int r = 0; r < 4; ++r) {
                float den = fmaxf(qa[r] * nnl[ni], EPS);
                rs[r] += __expf(acc[mi][ni][r] * (TEMP_INV / den));
            }
        }
        #pragma unroll
        for (int m = 1; m < 16; m <<= 1) {
            #pragma unroll
            for (int r = 0; r < 4; ++r) rs[r] += __shfl_xor(rs[r], m, 64);
        }
        if (lc == 0) {
            #pragma unroll
            for (int r = 0; r < 4; ++r) atomicAdd(&rowsum[rbase + r], rs[r]);
        }
    }
}

// ---------------------------------------------------------------------------
// Kernel 3: loss = mean_b( log((s1 + s2) / s1) ), s2 = rowsum/N
// ---------------------------------------------------------------------------
__global__ __launch_bounds__(256) void finalize_kernel(
    const float* __restrict__ s1, const float* __restrict__ rowsum,
    float* __restrict__ out, int B, float invN)
{
    __shared__ float red[4];
    float acc = 0.f;
    for (int b = threadIdx.x; b < B; b += 256) {
        float a = s1[b];
        float s2 = rowsum[b] * invN;
        acc += logf((a + s2) / a);
    }
    #pragma unroll
    for (int off = 32; off > 0; off >>= 1) acc += __shfl_down(acc, off, 64);
    if ((threadIdx.x & 63) == 0) red[threadIdx.x >> 6] = acc;
    __syncthreads();
    if (threadIdx.x == 0)
        out[0] = (red[0] + red[1] + red[2] + red[3]) / (float)B;
}

extern "C" void kernel_launch(void* const* d_in, const int* in_sizes, int n_in,
                              void* d_out, int out_size, void* d_ws, size_t ws_size,
                              hipStream_t stream) {
    const float* q   = (const float*)d_in[0];
    const float* p   = (const float*)d_in[1];
    const float* neg = (const float*)d_in[2];
    const int B = in_sizes[0] / D;
    const int N = in_sizes[2] / D;

    char* ws = (char*)d_ws;
    __bf16* Qb     = (__bf16*)ws;
    __bf16* Nb     = (__bf16*)(ws + (size_t)B * D * 2);
    float*  qn     = (float*)(ws + (size_t)(B + N) * D * 2);
    float*  nn     = qn + B;
    float*  s1     = nn + N;
    float*  rowsum = s1 + B;

    prep_kernel<<<B + N, 256, 0, stream>>>(q, p, neg, Qb, Nb, qn, nn, s1, rowsum, B);
    gemm_exp_rowsum<<<dim3(N / 128, B / 128), 256, 0, stream>>>(Qb, Nb, qn, nn, rowsum);
    finalize_kernel<<<1, 256, 0, stream>>>(s1, rowsum, (float*)d_out, B, 1.0f / (float)N);
}

// Round 2
// 355.516 us; speedup vs baseline: 1.0764x; 1.0764x over previous
//
#include <hip/hip_runtime.h>
#include <hip/hip_bf16.h>

#define D 1024
#define TEMP_INV (1.0f / 0.92f)
#define EPS 1e-6f

typedef __bf16 bf16x4_t __attribute__((ext_vector_type(4)));
typedef __bf16 bf16x8_t __attribute__((ext_vector_type(8)));
typedef float f32x4_t __attribute__((ext_vector_type(4)));

typedef __attribute__((address_space(3))) void as3_void;
typedef const __attribute__((address_space(1))) void as1_void_c;

__device__ __forceinline__ void async_copy16(const __bf16* g, __bf16* l) {
    __builtin_amdgcn_global_load_lds((as1_void_c*)g, (as3_void*)l, 16, 0, 0);
}

// ---------------------------------------------------------------------------
// Kernel 1: convert Q,Neg to bf16; compute qn, nn, s1=exp(pos_sim/T); zero rowsum.
// One WAVE per row (4 rows/block), 4 coalesced float4 loads per lane, wave-level
// shuffle reduction (no __syncthreads).
// ---------------------------------------------------------------------------
__global__ __launch_bounds__(256) void prep_kernel(
    const float* __restrict__ q, const float* __restrict__ p,
    const float* __restrict__ neg,
    __bf16* __restrict__ Qb, __bf16* __restrict__ Nb,
    float* __restrict__ qn, float* __restrict__ nn,
    float* __restrict__ s1, float* __restrict__ rowsum, int B)
{
    const int lane = threadIdx.x & 63;
    const int wid  = threadIdx.x >> 6;
    const int row  = blockIdx.x * 4 + wid;

    if (row < B) {
        const float4* qr = (const float4*)(q + (size_t)row * D);
        const float4* pr = (const float4*)(p + (size_t)row * D);
        bf16x4_t* qo = (bf16x4_t*)(Qb + (size_t)row * D);
        float qq = 0.f, pp = 0.f, qp = 0.f;
        #pragma unroll
        for (int i = 0; i < 4; ++i) {
            const int idx = i * 64 + lane;
            const float4 qv = qr[idx];
            const float4 pv = pr[idx];
            bf16x4_t o;
            o[0] = (__bf16)qv.x; o[1] = (__bf16)qv.y; o[2] = (__bf16)qv.z; o[3] = (__bf16)qv.w;
            qo[idx] = o;
            qq += qv.x*qv.x + qv.y*qv.y + qv.z*qv.z + qv.w*qv.w;
            pp += pv.x*pv.x + pv.y*pv.y + pv.z*pv.z + pv.w*pv.w;
            qp += qv.x*pv.x + qv.y*pv.y + qv.z*pv.z + qv.w*pv.w;
        }
        #pragma unroll
        for (int off = 32; off > 0; off >>= 1) {
            qq += __shfl_down(qq, off, 64);
            pp += __shfl_down(pp, off, 64);
            qp += __shfl_down(qp, off, 64);
        }
        if (lane == 0) {
            float qnv = sqrtf(qq);
            qn[row] = qnv;
            float den = fmaxf(qnv * sqrtf(pp), EPS);
            s1[row] = expf((qp / den) * TEMP_INV);
            rowsum[row] = 0.0f;
        }
    } else {
        const int r2 = row - B;
        const float4* nr = (const float4*)(neg + (size_t)r2 * D);
        bf16x4_t* no = (bf16x4_t*)(Nb + (size_t)r2 * D);
        float ss = 0.f;
        #pragma unroll
        for (int i = 0; i < 4; ++i) {
            const int idx = i * 64 + lane;
            const float4 nv = nr[idx];
            bf16x4_t o;
            o[0] = (__bf16)nv.x; o[1] = (__bf16)nv.y; o[2] = (__bf16)nv.z; o[3] = (__bf16)nv.w;
            no[idx] = o;
            ss += nv.x*nv.x + nv.y*nv.y + nv.z*nv.z + nv.w*nv.w;
        }
        #pragma unroll
        for (int off = 32; off > 0; off >>= 1) ss += __shfl_down(ss, off, 64);
        if (lane == 0) nn[r2] = sqrtf(ss);
    }
}

// ---------------------------------------------------------------------------
// Kernel 2: fused C = Qb * Nb^T (bf16 MFMA), epilogue exp + row-sum.
// 128x128 tile, BK=64, 256 threads = 4 waves in 2x2; each wave 64x64 via
// 4x4 grid of 16x16x32 MFMA fragments.
//
// LDS layout XOR-swizzle: 16B chunk (row, c) lives at byte offset
//   row*128 + (c ^ (row&7))*16.
// Write side keeps global_load_lds's "base + tid*16" dest by permuting WHICH
// global chunk each thread fetches: thread slot s of row r fetches chunk
// c = s ^ (r&7). Read side applies the same XOR -> per-quad phases hit a
// permutation of the 8 bank-groups (worst 2-way = free, m136).
// ---------------------------------------------------------------------------
__global__ __launch_bounds__(256) void gemm_exp_rowsum(
    const __bf16* __restrict__ Qb, const __bf16* __restrict__ Nb,
    const float* __restrict__ qn, const float* __restrict__ nn,
    float* __restrict__ rowsum)
{
    __shared__ __bf16 As[128 * 64];
    __shared__ __bf16 Bs[128 * 64];

    const int tid = threadIdx.x;
    const int i0 = blockIdx.y * 128;   // Q rows
    const int j0 = blockIdx.x * 128;   // Neg rows

    const int lane = tid & 63;
    const int wid  = tid >> 6;
    const int wm   = wid & 1;          // wave row (2x2 wave grid)
    const int wn   = wid >> 1;         // wave col
    const int quad = lane >> 4;
    const int lc   = lane & 15;
    const int xsw  = lc & 7;           // read-side XOR key (row&7 == lc&7)

    f32x4_t acc[4][4];
    #pragma unroll
    for (int mi = 0; mi < 4; ++mi)
        #pragma unroll
        for (int ni = 0; ni < 4; ++ni)
            acc[mi][ni] = (f32x4_t){0.f, 0.f, 0.f, 0.f};

    // staging: thread t handles row r_in = t>>3 (within each 32-row round),
    // stored slot s = t&7 -> fetches global chunk c = s ^ (r_in&7).
    const int r_in = tid >> 3;
    const int slot = tid & 7;
    const int csw  = slot ^ (r_in & 7);
    const __bf16* ga = Qb + (size_t)(i0 + r_in) * D + csw * 8;
    const __bf16* gb = Nb + (size_t)(j0 + r_in) * D + csw * 8;
    __bf16* la = As + tid * 8;
    __bf16* lb = Bs + tid * 8;

    // LDS read row bases (element units): row = wm*64 + mi*16 + lc, 64 el/row
    const __bf16* Abase = As + (size_t)(wm * 64 + lc) * 64;
    const __bf16* Bbase = Bs + (size_t)(wn * 64 + lc) * 64;

    for (int kt = 0; kt < D; kt += 64) {
        __syncthreads();   // protect LDS from overwrite while others read
        #pragma unroll
        for (int c = 0; c < 4; ++c) {
            async_copy16(ga + kt + c * (32 * D), la + c * 2048);
            async_copy16(gb + kt + c * (32 * D), lb + c * 2048);
        }
        __syncthreads();   // drains vmcnt(0) before s_barrier

        #pragma unroll
        for (int ks = 0; ks < 2; ++ks) {
            const int chunk = ((ks * 4 + quad) ^ xsw) * 8;  // swizzled k-chunk offset (elements)
            bf16x8_t af[4], bf[4];
            #pragma unroll
            for (int mi = 0; mi < 4; ++mi)
                af[mi] = *(const bf16x8_t*)(Abase + mi * (16 * 64) + chunk);
            #pragma unroll
            for (int ni = 0; ni < 4; ++ni)
                bf[ni] = *(const bf16x8_t*)(Bbase + ni * (16 * 64) + chunk);
            #pragma unroll
            for (int mi = 0; mi < 4; ++mi)
                #pragma unroll
                for (int ni = 0; ni < 4; ++ni)
                    acc[mi][ni] = __builtin_amdgcn_mfma_f32_16x16x32_bf16(
                        af[mi], bf[ni], acc[mi][ni], 0, 0, 0);
        }
    }

    // Epilogue: e = exp(c / (T * max(qn_i * nn_j, eps))), row-reduce, atomicAdd.
    // C/D layout (16x16x32): col = lane&15, row = quad*4 + reg.
    float nnl[4];
    #pragma unroll
    for (int ni = 0; ni < 4; ++ni)
        nnl[ni] = nn[j0 + wn * 64 + ni * 16 + lc];

    #pragma unroll
    for (int mi = 0; mi < 4; ++mi) {
        const int rbase = i0 + wm * 64 + mi * 16 + quad * 4;
        const float4 qv = *(const float4*)&qn[rbase];
        float qa[4] = {qv.x, qv.y, qv.z, qv.w};
        float rs[4] = {0.f, 0.f, 0.f, 0.f};
        #pragma unroll
        for (int ni = 0; ni < 4; ++ni) {
            #pragma unroll
            for (int r = 0; r < 4; ++r) {
                float den = fmaxf(qa[r] * nnl[ni], EPS);
                rs[r] += __expf(acc[mi][ni][r] * (TEMP_INV / den));
            }
        }
        #pragma unroll
        for (int m = 1; m < 16; m <<= 1) {
            #pragma unroll
            for (int r = 0; r < 4; ++r) rs[r] += __shfl_xor(rs[r], m, 64);
        }
        if (lc == 0) {
            #pragma unroll
            for (int r = 0; r < 4; ++r) atomicAdd(&rowsum[rbase + r], rs[r]);
        }
    }
}

// ---------------------------------------------------------------------------
// Kernel 3: loss = mean_b( log((s1 + s2) / s1) ), s2 = rowsum/N
// ---------------------------------------------------------------------------
__global__ __launch_bounds__(256) void finalize_kernel(
    const float* __restrict__ s1, const float* __restrict__ rowsum,
    float* __restrict__ out, int B, float invN)
{
    __shared__ float red[4];
    float acc = 0.f;
    for (int b = threadIdx.x; b < B; b += 256) {
        float a = s1[b];
        float s2 = rowsum[b] * invN;
        acc += logf((a + s2) / a);
    }
    #pragma unroll
    for (int off = 32; off > 0; off >>= 1) acc += __shfl_down(acc, off, 64);
    if ((threadIdx.x & 63) == 0) red[threadIdx.x >> 6] = acc;
    __syncthreads();
    if (threadIdx.x == 0)
        out[0] = (red[0] + red[1] + red[2] + red[3]) / (float)B;
}

extern "C" void kernel_launch(void* const* d_in, const int* in_sizes, int n_in,
                              void* d_out, int out_size, void* d_ws, size_t ws_size,
                              hipStream_t stream) {
    const float* q   = (const float*)d_in[0];
    const float* p   = (const float*)d_in[1];
    const float* neg = (const float*)d_in[2];
    const int B = in_sizes[0] / D;
    const int N = in_sizes[2] / D;

    char* ws = (char*)d_ws;
    __bf16* Qb     = (__bf16*)ws;
    __bf16* Nb     = (__bf16*)(ws + (size_t)B * D * 2);
    float*  qn     = (float*)(ws + (size_t)(B + N) * D * 2);
    float*  nn     = qn + B;
    float*  s1     = nn + N;
    float*  rowsum = s1 + B;

    prep_kernel<<<(B + N) / 4, 256, 0, stream>>>(q, p, neg, Qb, Nb, qn, nn, s1, rowsum, B);
    gemm_exp_rowsum<<<dim3(N / 128, B / 128), 256, 0, stream>>>(Qb, Nb, qn, nn, rowsum);
    finalize_kernel<<<1, 256, 0, stream>>>(s1, rowsum, (float*)d_out, B, 1.0f / (float)N);
}

// Round 3
// 281.531 us; speedup vs baseline: 1.3593x; 1.2628x over previous
//
#include <hip/hip_runtime.h>
#include <hip/hip_bf16.h>
#include <stdint.h>

#define D 1024
#define TEMP_INV (1.0f / 0.92f)
#define EPS 1e-6f

typedef float f32x4_t __attribute__((ext_vector_type(4)));
typedef int   i32x4_t __attribute__((ext_vector_type(4)));
typedef int   i32x8_t __attribute__((ext_vector_type(8)));

typedef __attribute__((address_space(3))) void as3_void;
typedef const __attribute__((address_space(1))) void as1_void_c;

__device__ __forceinline__ void async_copy16(const uint8_t* g, uint8_t* l) {
    __builtin_amdgcn_global_load_lds((as1_void_c*)g, (as3_void*)l, 16, 0, 0);
}

// ---------------------------------------------------------------------------
// Kernel 1: convert Q,Neg to fp8 e4m3; compute qn, nn, s1=exp(pos_sim/T);
// zero rowsum. One WAVE per row (4 rows/block); norms/pos path in exact fp32.
// ---------------------------------------------------------------------------
__global__ __launch_bounds__(256) void prep_kernel(
    const float* __restrict__ q, const float* __restrict__ p,
    const float* __restrict__ neg,
    uint8_t* __restrict__ Qb, uint8_t* __restrict__ Nb,
    float* __restrict__ qn, float* __restrict__ nn,
    float* __restrict__ s1, float* __restrict__ rowsum, int B)
{
    const int lane = threadIdx.x & 63;
    const int wid  = threadIdx.x >> 6;
    const int row  = blockIdx.x * 4 + wid;

    if (row < B) {
        const float4* qr = (const float4*)(q + (size_t)row * D);
        const float4* pr = (const float4*)(p + (size_t)row * D);
        int* qo = (int*)(Qb + (size_t)row * D);
        float qq = 0.f, pp = 0.f, qp = 0.f;
        #pragma unroll
        for (int i = 0; i < 4; ++i) {
            const int idx = i * 64 + lane;
            const float4 qv = qr[idx];
            const float4 pv = pr[idx];
            int pk = __builtin_amdgcn_cvt_pk_fp8_f32(qv.x, qv.y, 0, false);
            pk     = __builtin_amdgcn_cvt_pk_fp8_f32(qv.z, qv.w, pk, true);
            qo[idx] = pk;
            qq += qv.x*qv.x + qv.y*qv.y + qv.z*qv.z + qv.w*qv.w;
            pp += pv.x*pv.x + pv.y*pv.y + pv.z*pv.z + pv.w*pv.w;
            qp += qv.x*pv.x + qv.y*pv.y + qv.z*pv.z + qv.w*pv.w;
        }
        #pragma unroll
        for (int off = 32; off > 0; off >>= 1) {
            qq += __shfl_down(qq, off, 64);
            pp += __shfl_down(pp, off, 64);
            qp += __shfl_down(qp, off, 64);
        }
        if (lane == 0) {
            float qnv = sqrtf(qq);
            qn[row] = qnv;
            float den = fmaxf(qnv * sqrtf(pp), EPS);
            s1[row] = expf((qp / den) * TEMP_INV);
            rowsum[row] = 0.0f;
        }
    } else {
        const int r2 = row - B;
        const float4* nr = (const float4*)(neg + (size_t)r2 * D);
        int* no = (int*)(Nb + (size_t)r2 * D);
        float ss = 0.f;
        #pragma unroll
        for (int i = 0; i < 4; ++i) {
            const int idx = i * 64 + lane;
            const float4 nv = nr[idx];
            int pk = __builtin_amdgcn_cvt_pk_fp8_f32(nv.x, nv.y, 0, false);
            pk     = __builtin_amdgcn_cvt_pk_fp8_f32(nv.z, nv.w, pk, true);
            no[idx] = pk;
            ss += nv.x*nv.x + nv.y*nv.y + nv.z*nv.z + nv.w*nv.w;
        }
        #pragma unroll
        for (int off = 32; off > 0; off >>= 1) ss += __shfl_down(ss, off, 64);
        if (lane == 0) nn[r2] = sqrtf(ss);
    }
}

// ---------------------------------------------------------------------------
// Kernel 2: fused C = Qb * Nb^T via MX-fp8 mfma_scale 16x16x128 (unit scales),
// epilogue exp + row-sum. 128x128 tile, BK=128 fp8 (rows = 128 B = 8 chunks
// of 16 B -> identical XOR-swizzle math as the verified bf16 version; round 2
// measured 0 bank conflicts with this exact address pattern).
// A/B frag: lane holds 32 contiguous k-bytes at row/col = lane&15,
// k = (lane>>4)*32. C/D layout is shape-determined (same as 16x16x32).
// ---------------------------------------------------------------------------
__global__ __launch_bounds__(256) void gemm_exp_rowsum(
    const uint8_t* __restrict__ Qb, const uint8_t* __restrict__ Nb,
    const float* __restrict__ qn, const float* __restrict__ nn,
    float* __restrict__ rowsum)
{
    __shared__ uint8_t As[128 * 128];   // 16 KB
    __shared__ uint8_t Bs[128 * 128];   // 16 KB

    const int tid = threadIdx.x;
    const int i0 = blockIdx.y * 128;   // Q rows
    const int j0 = blockIdx.x * 128;   // Neg rows

    const int lane = tid & 63;
    const int wid  = tid >> 6;
    const int wm   = wid & 1;          // wave row (2x2 wave grid)
    const int wn   = wid >> 1;         // wave col
    const int quad = lane >> 4;
    const int lc   = lane & 15;
    const int xsw  = lc & 7;           // read-side XOR key

    f32x4_t acc[4][4];
    #pragma unroll
    for (int mi = 0; mi < 4; ++mi)
        #pragma unroll
        for (int ni = 0; ni < 4; ++ni)
            acc[mi][ni] = (f32x4_t){0.f, 0.f, 0.f, 0.f};

    // staging: thread t = row r_in = t>>3 (per 32-row round), slot s = t&7;
    // fetches global 16B chunk c = s ^ (r_in&7); LDS dest = base + tid*16.
    const int r_in = tid >> 3;
    const int slot = tid & 7;
    const int csw  = slot ^ (r_in & 7);
    const uint8_t* ga = Qb + (size_t)(i0 + r_in) * D + csw * 16;
    const uint8_t* gb = Nb + (size_t)(j0 + r_in) * D + csw * 16;
    uint8_t* la = As + tid * 16;
    uint8_t* lb = Bs + tid * 16;

    // LDS read bases: row = wm*64 + mi*16 + lc, 128 B/row
    const uint8_t* Abase = As + (size_t)(wm * 64 + lc) * 128;
    const uint8_t* Bbase = Bs + (size_t)(wn * 64 + lc) * 128;
    // swizzled byte offsets of the lane's two 16B half-frags within a row
    const int c0 = ((quad * 2 + 0) ^ xsw) * 16;
    const int c1 = ((quad * 2 + 1) ^ xsw) * 16;

    for (int kt = 0; kt < D; kt += 128) {
        __syncthreads();   // protect LDS while other waves still reading
        #pragma unroll
        for (int c = 0; c < 4; ++c) {
            async_copy16(ga + kt + c * (32 * D), la + c * 4096);
            async_copy16(gb + kt + c * (32 * D), lb + c * 4096);
        }
        __syncthreads();   // drains vmcnt(0) before s_barrier

        i32x8_t bfr[4];
        #pragma unroll
        for (int ni = 0; ni < 4; ++ni) {
            i32x4_t lo = *(const i32x4_t*)(Bbase + ni * 2048 + c0);
            i32x4_t hi = *(const i32x4_t*)(Bbase + ni * 2048 + c1);
            i32x8_t f;
            f[0]=lo[0]; f[1]=lo[1]; f[2]=lo[2]; f[3]=lo[3];
            f[4]=hi[0]; f[5]=hi[1]; f[6]=hi[2]; f[7]=hi[3];
            bfr[ni] = f;
        }
        #pragma unroll
        for (int mi = 0; mi < 4; ++mi) {
            i32x4_t lo = *(const i32x4_t*)(Abase + mi * 2048 + c0);
            i32x4_t hi = *(const i32x4_t*)(Abase + mi * 2048 + c1);
            i32x8_t af;
            af[0]=lo[0]; af[1]=lo[1]; af[2]=lo[2]; af[3]=lo[3];
            af[4]=hi[0]; af[5]=hi[1]; af[6]=hi[2]; af[7]=hi[3];
            #pragma unroll
            for (int ni = 0; ni < 4; ++ni)
                acc[mi][ni] = __builtin_amdgcn_mfma_scale_f32_16x16x128_f8f6f4(
                    af, bfr[ni], acc[mi][ni],
                    0 /*cbsz: A=fp8 e4m3*/, 0 /*blgp: B=fp8 e4m3*/,
                    0, 127 /*scale A = 2^0*/, 0, 127 /*scale B = 2^0*/);
        }
    }

    // Epilogue: e = exp(c / (T * max(qn_i * nn_j, eps))), row-reduce, atomicAdd.
    // C/D layout (16x16): col = lane&15, row = quad*4 + reg.
    float nnl[4];
    #pragma unroll
    for (int ni = 0; ni < 4; ++ni)
        nnl[ni] = nn[j0 + wn * 64 + ni * 16 + lc];

    #pragma unroll
    for (int mi = 0; mi < 4; ++mi) {
        const int rbase = i0 + wm * 64 + mi * 16 + quad * 4;
        const float4 qv = *(const float4*)&qn[rbase];
        float qa[4] = {qv.x, qv.y, qv.z, qv.w};
        float rs[4] = {0.f, 0.f, 0.f, 0.f};
        #pragma unroll
        for (int ni = 0; ni < 4; ++ni) {
            #pragma unroll
            for (int r = 0; r < 4; ++r) {
                float den = fmaxf(qa[r] * nnl[ni], EPS);
                rs[r] += __expf(acc[mi][ni][r] * (TEMP_INV / den));
            }
        }
        #pragma unroll
        for (int m = 1; m < 16; m <<= 1) {
            #pragma unroll
            for (int r = 0; r < 4; ++r) rs[r] += __shfl_xor(rs[r], m, 64);
        }
        if (lc == 0) {
            #pragma unroll
            for (int r = 0; r < 4; ++r) atomicAdd(&rowsum[rbase + r], rs[r]);
        }
    }
}

// ---------------------------------------------------------------------------
// Kernel 3: loss = mean_b( log((s1 + s2) / s1) ), s2 = rowsum/N
// ---------------------------------------------------------------------------
__global__ __launch_bounds__(256) void finalize_kernel(
    const float* __restrict__ s1, const float* __restrict__ rowsum,
    float* __restrict__ out, int B, float invN)
{
    __shared__ float red[4];
    float acc = 0.f;
    for (int b = threadIdx.x; b < B; b += 256) {
        float a = s1[b];
        float s2 = rowsum[b] * invN;
        acc += logf((a + s2) / a);
    }
    #pragma unroll
    for (int off = 32; off > 0; off >>= 1) acc += __shfl_down(acc, off, 64);
    if ((threadIdx.x & 63) == 0) red[threadIdx.x >> 6] = acc;
    __syncthreads();
    if (threadIdx.x == 0)
        out[0] = (red[0] + red[1] + red[2] + red[3]) / (float)B;
}

extern "C" void kernel_launch(void* const* d_in, const int* in_sizes, int n_in,
                              void* d_out, int out_size, void* d_ws, size_t ws_size,
                              hipStream_t stream) {
    const float* q   = (const float*)d_in[0];
    const float* p   = (const float*)d_in[1];
    const float* neg = (const float*)d_in[2];
    const int B = in_sizes[0] / D;
    const int N = in_sizes[2] / D;

    char* ws = (char*)d_ws;
    uint8_t* Qb     = (uint8_t*)ws;
    uint8_t* Nb     = (uint8_t*)(ws + (size_t)B * D);
    float*   qn     = (float*)(ws + (size_t)(B + N) * D);
    float*   nn     = qn + B;
    float*   s1     = nn + N;
    float*   rowsum = s1 + B;

    prep_kernel<<<(B + N) / 4, 256, 0, stream>>>(q, p, neg, Qb, Nb, qn, nn, s1, rowsum, B);
    gemm_exp_rowsum<<<dim3(N / 128, B / 128), 256, 0, stream>>>(Qb, Nb, qn, nn, rowsum);
    finalize_kernel<<<1, 256, 0, stream>>>(s1, rowsum, (float*)d_out, B, 1.0f / (float)N);
}

// Round 4
// 275.595 us; speedup vs baseline: 1.3886x; 1.0215x over previous
//
#include <hip/hip_runtime.h>
#include <hip/hip_bf16.h>
#include <stdint.h>

#define D 1024
#define TEMP_INV (1.0f / 0.92f)
#define EPS 1e-6f

typedef float f32x4_t __attribute__((ext_vector_type(4)));
typedef int   i32x4_t __attribute__((ext_vector_type(4)));
typedef int   i32x8_t __attribute__((ext_vector_type(8)));

typedef __attribute__((address_space(3))) void as3_void;
typedef const __attribute__((address_space(1))) void as1_void_c;

__device__ __forceinline__ void async_copy16(const uint8_t* g, uint8_t* l) {
    __builtin_amdgcn_global_load_lds((as1_void_c*)g, (as3_void*)l, 16, 0, 0);
}

// ---------------------------------------------------------------------------
// Kernel 1: convert Q,Neg to fp8 e4m3; compute qn, nn, s1=exp(pos_sim/T);
// zero rowsum. One WAVE per row (4 rows/block); norms/pos path in exact fp32.
// ---------------------------------------------------------------------------
__global__ __launch_bounds__(256) void prep_kernel(
    const float* __restrict__ q, const float* __restrict__ p,
    const float* __restrict__ neg,
    uint8_t* __restrict__ Qb, uint8_t* __restrict__ Nb,
    float* __restrict__ qn, float* __restrict__ nn,
    float* __restrict__ s1, float* __restrict__ rowsum, int B)
{
    const int lane = threadIdx.x & 63;
    const int wid  = threadIdx.x >> 6;
    const int row  = blockIdx.x * 4 + wid;

    if (row < B) {
        const float4* qr = (const float4*)(q + (size_t)row * D);
        const float4* pr = (const float4*)(p + (size_t)row * D);
        int* qo = (int*)(Qb + (size_t)row * D);
        float qq = 0.f, pp = 0.f, qp = 0.f;
        #pragma unroll
        for (int i = 0; i < 4; ++i) {
            const int idx = i * 64 + lane;
            const float4 qv = qr[idx];
            const float4 pv = pr[idx];
            int pk = __builtin_amdgcn_cvt_pk_fp8_f32(qv.x, qv.y, 0, false);
            pk     = __builtin_amdgcn_cvt_pk_fp8_f32(qv.z, qv.w, pk, true);
            qo[idx] = pk;
            qq += qv.x*qv.x + qv.y*qv.y + qv.z*qv.z + qv.w*qv.w;
            pp += pv.x*pv.x + pv.y*pv.y + pv.z*pv.z + pv.w*pv.w;
            qp += qv.x*pv.x + qv.y*pv.y + qv.z*pv.z + qv.w*pv.w;
        }
        #pragma unroll
        for (int off = 32; off > 0; off >>= 1) {
            qq += __shfl_down(qq, off, 64);
            pp += __shfl_down(pp, off, 64);
            qp += __shfl_down(qp, off, 64);
        }
        if (lane == 0) {
            float qnv = sqrtf(qq);
            qn[row] = qnv;
            float den = fmaxf(qnv * sqrtf(pp), EPS);
            s1[row] = expf((qp / den) * TEMP_INV);
            rowsum[row] = 0.0f;
        }
    } else {
        const int r2 = row - B;
        const float4* nr = (const float4*)(neg + (size_t)r2 * D);
        int* no = (int*)(Nb + (size_t)r2 * D);
        float ss = 0.f;
        #pragma unroll
        for (int i = 0; i < 4; ++i) {
            const int idx = i * 64 + lane;
            const float4 nv = nr[idx];
            int pk = __builtin_amdgcn_cvt_pk_fp8_f32(nv.x, nv.y, 0, false);
            pk     = __builtin_amdgcn_cvt_pk_fp8_f32(nv.z, nv.w, pk, true);
            no[idx] = pk;
            ss += nv.x*nv.x + nv.y*nv.y + nv.z*nv.z + nv.w*nv.w;
        }
        #pragma unroll
        for (int off = 32; off > 0; off >>= 1) ss += __shfl_down(ss, off, 64);
        if (lane == 0) nn[r2] = sqrtf(ss);
    }
}

// ---------------------------------------------------------------------------
// Kernel 2: fused C = Qb * Nb^T via MX-fp8 mfma_scale 16x16x128 (unit scales),
// epilogue exp + row-sum. 128x128 tile, BK=128 fp8.
//
// LDS chunk permutation: 16B chunk c of row r stored at slot pi(c)^(r&7),
// pi(c) = (c>>1)|((c&1)<<2)  (even chunks -> slots 0..3, odd -> 4..7).
// Lane (quad q, lc) needs chunks {2q, 2q+1}:
//   slot_lo = q ^ (lc&7), slot_hi = slot_lo ^ 4
// -> bit-identical to round 2's measured-ZERO-conflict read patterns.
// Write side: thread t (row r=t>>3, slot s=t&7) fetches global chunk
//   c = ((v&3)<<1)|(v>>2), v = s^(r&7);  LDS dest stays base + t*16.
// Frags loaded via union so ds_read_b128 lands directly in the mfma operand
// tuple (no repack v_movs).
// ---------------------------------------------------------------------------
__global__ __launch_bounds__(256) void gemm_exp_rowsum(
    const uint8_t* __restrict__ Qb, const uint8_t* __restrict__ Nb,
    const float* __restrict__ qn, const float* __restrict__ nn,
    float* __restrict__ rowsum)
{
    __shared__ uint8_t As[128 * 128];   // 16 KB
    __shared__ uint8_t Bs[128 * 128];   // 16 KB

    const int tid = threadIdx.x;
    const int i0 = blockIdx.y * 128;   // Q rows
    const int j0 = blockIdx.x * 128;   // Neg rows

    const int lane = tid & 63;
    const int wid  = tid >> 6;
    const int wm   = wid & 1;          // wave row (2x2 wave grid)
    const int wn   = wid >> 1;         // wave col
    const int quad = lane >> 4;
    const int lc   = lane & 15;
    const int xsw  = lc & 7;           // read-side XOR key

    f32x4_t acc[4][4];
    #pragma unroll
    for (int mi = 0; mi < 4; ++mi)
        #pragma unroll
        for (int ni = 0; ni < 4; ++ni)
            acc[mi][ni] = (f32x4_t){0.f, 0.f, 0.f, 0.f};

    // staging: thread t: row r_in = t>>3 (per 32-row round), slot s = t&7;
    // fetch global chunk c = pi^-1(s ^ (r_in&7)); LDS dest = base + t*16.
    const int r_in = tid >> 3;
    const int slot = tid & 7;
    const int v    = slot ^ (r_in & 7);
    const int csw  = ((v & 3) << 1) | (v >> 2);
    const uint8_t* ga = Qb + (size_t)(i0 + r_in) * D + csw * 16;
    const uint8_t* gb = Nb + (size_t)(j0 + r_in) * D + csw * 16;
    uint8_t* la = As + tid * 16;
    uint8_t* lb = Bs + tid * 16;

    // LDS read bases: row = wm*64 + mi*16 + lc, 128 B/row
    const uint8_t* Abase = As + (size_t)(wm * 64 + lc) * 128;
    const uint8_t* Bbase = Bs + (size_t)(wn * 64 + lc) * 128;
    const int slo = (quad ^ xsw) * 16;   // slot of chunk 2q
    const int shi = slo ^ 64;            // slot of chunk 2q+1 (slot^4)*16

    union Frag { i32x8_t v8; i32x4_t v4[2]; };

    for (int kt = 0; kt < D; kt += 128) {
        __syncthreads();   // protect LDS while other waves still reading
        #pragma unroll
        for (int c = 0; c < 4; ++c) {
            async_copy16(ga + kt + c * (32 * D), la + c * 4096);
            async_copy16(gb + kt + c * (32 * D), lb + c * 4096);
        }
        __syncthreads();   // drains vmcnt(0) before s_barrier

        Frag bfr[4];
        #pragma unroll
        for (int ni = 0; ni < 4; ++ni) {
            bfr[ni].v4[0] = *(const i32x4_t*)(Bbase + ni * 2048 + slo);
            bfr[ni].v4[1] = *(const i32x4_t*)(Bbase + ni * 2048 + shi);
        }
        #pragma unroll
        for (int mi = 0; mi < 4; ++mi) {
            Frag af;
            af.v4[0] = *(const i32x4_t*)(Abase + mi * 2048 + slo);
            af.v4[1] = *(const i32x4_t*)(Abase + mi * 2048 + shi);
            #pragma unroll
            for (int ni = 0; ni < 4; ++ni)
                acc[mi][ni] = __builtin_amdgcn_mfma_scale_f32_16x16x128_f8f6f4(
                    af.v8, bfr[ni].v8, acc[mi][ni],
                    0 /*cbsz: A=fp8 e4m3*/, 0 /*blgp: B=fp8 e4m3*/,
                    0, 127 /*scale A = 2^0*/, 0, 127 /*scale B = 2^0*/);
        }
    }

    // Epilogue: e = exp(c / (T * max(qn_i * nn_j, eps))), row-reduce, atomicAdd.
    // C/D layout (16x16): col = lane&15, row = quad*4 + reg.
    float nnl[4];
    #pragma unroll
    for (int ni = 0; ni < 4; ++ni)
        nnl[ni] = nn[j0 + wn * 64 + ni * 16 + lc];

    #pragma unroll
    for (int mi = 0; mi < 4; ++mi) {
        const int rbase = i0 + wm * 64 + mi * 16 + quad * 4;
        const float4 qv = *(const float4*)&qn[rbase];
        float qa[4] = {qv.x, qv.y, qv.z, qv.w};
        float rs[4] = {0.f, 0.f, 0.f, 0.f};
        #pragma unroll
        for (int ni = 0; ni < 4; ++ni) {
            #pragma unroll
            for (int r = 0; r < 4; ++r) {
                float den = fmaxf(qa[r] * nnl[ni], EPS);
                rs[r] += __expf(acc[mi][ni][r] * (TEMP_INV / den));
            }
        }
        #pragma unroll
        for (int m = 1; m < 16; m <<= 1) {
            #pragma unroll
            for (int r = 0; r < 4; ++r) rs[r] += __shfl_xor(rs[r], m, 64);
        }
        if (lc == 0) {
            #pragma unroll
            for (int r = 0; r < 4; ++r) atomicAdd(&rowsum[rbase + r], rs[r]);
        }
    }
}

// ---------------------------------------------------------------------------
// Kernel 3: loss = mean_b( log((s1 + s2) / s1) ), s2 = rowsum/N
// ---------------------------------------------------------------------------
__global__ __launch_bounds__(256) void finalize_kernel(
    const float* __restrict__ s1, const float* __restrict__ rowsum,
    float* __restrict__ out, int B, float invN)
{
    __shared__ float red[4];
    float acc = 0.f;
    for (int b = threadIdx.x; b < B; b += 256) {
        float a = s1[b];
        float s2 = rowsum[b] * invN;
        acc += logf((a + s2) / a);
    }
    #pragma unroll
    for (int off = 32; off > 0; off >>= 1) acc += __shfl_down(acc, off, 64);
    if ((threadIdx.x & 63) == 0) red[threadIdx.x >> 6] = acc;
    __syncthreads();
    if (threadIdx.x == 0)
        out[0] = (red[0] + red[1] + red[2] + red[3]) / (float)B;
}

extern "C" void kernel_launch(void* const* d_in, const int* in_sizes, int n_in,
                              void* d_out, int out_size, void* d_ws, size_t ws_size,
                              hipStream_t stream) {
    const float* q   = (const float*)d_in[0];
    const float* p   = (const float*)d_in[1];
    const float* neg = (const float*)d_in[2];
    const int B = in_sizes[0] / D;
    const int N = in_sizes[2] / D;

    char* ws = (char*)d_ws;
    uint8_t* Qb     = (uint8_t*)ws;
    uint8_t* Nb     = (uint8_t*)(ws + (size_t)B * D);
    float*   qn     = (float*)(ws + (size_t)(B + N) * D);
    float*   nn     = qn + B;
    float*   s1     = nn + N;
    float*   rowsum = s1 + B;

    prep_kernel<<<(B + N) / 4, 256, 0, stream>>>(q, p, neg, Qb, Nb, qn, nn, s1, rowsum, B);
    gemm_exp_rowsum<<<dim3(N / 128, B / 128), 256, 0, stream>>>(Qb, Nb, qn, nn, rowsum);
    finalize_kernel<<<1, 256, 0, stream>>>(s1, rowsum, (float*)d_out, B, 1.0f / (float)N);
}

// Round 5
// 241.541 us; speedup vs baseline: 1.5843x; 1.1410x over previous
//
#include <hip/hip_runtime.h>
#include <hip/hip_bf16.h>
#include <stdint.h>

#define D 1024
#define TEMP_INV (1.0f / 0.92f)
#define LOG2E 1.44269504f
#define EPS 1e-6f

typedef float f32x4_t __attribute__((ext_vector_type(4)));
typedef int   i32x4_t __attribute__((ext_vector_type(4)));
typedef int   i32x8_t __attribute__((ext_vector_type(8)));

typedef __attribute__((address_space(3))) void as3_void;
typedef const __attribute__((address_space(1))) void as1_void_c;

__device__ __forceinline__ void async_copy16(const uint8_t* g, uint8_t* l) {
    __builtin_amdgcn_global_load_lds((as1_void_c*)g, (as3_void*)l, 16, 0, 0);
}

// ---------------------------------------------------------------------------
// Kernel 1: convert Q,Neg to fp8 e4m3; compute iq = T^-1*log2e/qn,
// in = 1/nn, s1 = exp(pos_sim/T) (exact fp32 path); zero rowsum.
// One WAVE per row (4 rows/block).
// ---------------------------------------------------------------------------
__global__ __launch_bounds__(256) void prep_kernel(
    const float* __restrict__ q, const float* __restrict__ p,
    const float* __restrict__ neg,
    uint8_t* __restrict__ Qb, uint8_t* __restrict__ Nb,
    float* __restrict__ iq, float* __restrict__ inx,
    float* __restrict__ s1, float* __restrict__ rowsum, int B)
{
    const int lane = threadIdx.x & 63;
    const int wid  = threadIdx.x >> 6;
    const int row  = blockIdx.x * 4 + wid;

    if (row < B) {
        const float4* qr = (const float4*)(q + (size_t)row * D);
        const float4* pr = (const float4*)(p + (size_t)row * D);
        int* qo = (int*)(Qb + (size_t)row * D);
        float qq = 0.f, pp = 0.f, qp = 0.f;
        #pragma unroll
        for (int i = 0; i < 4; ++i) {
            const int idx = i * 64 + lane;
            const float4 qv = qr[idx];
            const float4 pv = pr[idx];
            int pk = __builtin_amdgcn_cvt_pk_fp8_f32(qv.x, qv.y, 0, false);
            pk     = __builtin_amdgcn_cvt_pk_fp8_f32(qv.z, qv.w, pk, true);
            qo[idx] = pk;
            qq += qv.x*qv.x + qv.y*qv.y + qv.z*qv.z + qv.w*qv.w;
            pp += pv.x*pv.x + pv.y*pv.y + pv.z*pv.z + pv.w*pv.w;
            qp += qv.x*pv.x + qv.y*pv.y + qv.z*pv.z + qv.w*pv.w;
        }
        #pragma unroll
        for (int off = 32; off > 0; off >>= 1) {
            qq += __shfl_down(qq, off, 64);
            pp += __shfl_down(pp, off, 64);
            qp += __shfl_down(qp, off, 64);
        }
        if (lane == 0) {
            float qnv = sqrtf(qq);
            iq[row] = (TEMP_INV * LOG2E) / fmaxf(qnv, 1e-20f);
            float den = fmaxf(qnv * sqrtf(pp), EPS);
            s1[row] = expf((qp / den) * TEMP_INV);   // exact reference path
            rowsum[row] = 0.0f;
        }
    } else {
        const int r2 = row - B;
        const float4* nr = (const float4*)(neg + (size_t)r2 * D);
        int* no = (int*)(Nb + (size_t)r2 * D);
        float ss = 0.f;
        #pragma unroll
        for (int i = 0; i < 4; ++i) {
            const int idx = i * 64 + lane;
            const float4 nv = nr[idx];
            int pk = __builtin_amdgcn_cvt_pk_fp8_f32(nv.x, nv.y, 0, false);
            pk     = __builtin_amdgcn_cvt_pk_fp8_f32(nv.z, nv.w, pk, true);
            no[idx] = pk;
            ss += nv.x*nv.x + nv.y*nv.y + nv.z*nv.z + nv.w*nv.w;
        }
        #pragma unroll
        for (int off = 32; off > 0; off >>= 1) ss += __shfl_down(ss, off, 64);
        if (lane == 0) inx[r2] = 1.0f / fmaxf(sqrtf(ss), 1e-20f);
    }
}

// ---------------------------------------------------------------------------
// Kernel 2: fused C = Qb * Nb^T via MX-fp8 mfma_scale 16x16x128 (unit scales),
// epilogue exp2(dot * iq_i * in_j) + row-sum. 128x128 tile, BK=128 fp8.
// LDS chunk permutation pi(c) = (c>>1)|((c&1)<<2), measured 0 bank conflicts
// (round 4). K-loop is bit-identical to round 4; only the epilogue math
// changed (divisions -> precomputed-reciprocal muls, expf -> v_exp).
// ---------------------------------------------------------------------------
__global__ __launch_bounds__(256) void gemm_exp_rowsum(
    const uint8_t* __restrict__ Qb, const uint8_t* __restrict__ Nb,
    const float* __restrict__ iq, const float* __restrict__ inx,
    float* __restrict__ rowsum)
{
    __shared__ uint8_t As[128 * 128];   // 16 KB
    __shared__ uint8_t Bs[128 * 128];   // 16 KB

    const int tid = threadIdx.x;
    const int i0 = blockIdx.y * 128;   // Q rows
    const int j0 = blockIdx.x * 128;   // Neg rows

    const int lane = tid & 63;
    const int wid  = tid >> 6;
    const int wm   = wid & 1;          // wave row (2x2 wave grid)
    const int wn   = wid >> 1;         // wave col
    const int quad = lane >> 4;
    const int lc   = lane & 15;
    const int xsw  = lc & 7;           // read-side XOR key

    f32x4_t acc[4][4];
    #pragma unroll
    for (int mi = 0; mi < 4; ++mi)
        #pragma unroll
        for (int ni = 0; ni < 4; ++ni)
            acc[mi][ni] = (f32x4_t){0.f, 0.f, 0.f, 0.f};

    // staging: thread t: row r_in = t>>3 (per 32-row round), slot s = t&7;
    // fetch global chunk c = pi^-1(s ^ (r_in&7)); LDS dest = base + t*16.
    const int r_in = tid >> 3;
    const int slot = tid & 7;
    const int v    = slot ^ (r_in & 7);
    const int csw  = ((v & 3) << 1) | (v >> 2);
    const uint8_t* ga = Qb + (size_t)(i0 + r_in) * D + csw * 16;
    const uint8_t* gb = Nb + (size_t)(j0 + r_in) * D + csw * 16;
    uint8_t* la = As + tid * 16;
    uint8_t* lb = Bs + tid * 16;

    // LDS read bases: row = wm*64 + mi*16 + lc, 128 B/row
    const uint8_t* Abase = As + (size_t)(wm * 64 + lc) * 128;
    const uint8_t* Bbase = Bs + (size_t)(wn * 64 + lc) * 128;
    const int slo = (quad ^ xsw) * 16;   // slot of chunk 2q
    const int shi = slo ^ 64;            // slot of chunk 2q+1

    union Frag { i32x8_t v8; i32x4_t v4[2]; };

    for (int kt = 0; kt < D; kt += 128) {
        __syncthreads();   // protect LDS while other waves still reading
        #pragma unroll
        for (int c = 0; c < 4; ++c) {
            async_copy16(ga + kt + c * (32 * D), la + c * 4096);
            async_copy16(gb + kt + c * (32 * D), lb + c * 4096);
        }
        __syncthreads();   // drains vmcnt(0) before s_barrier

        Frag bfr[4];
        #pragma unroll
        for (int ni = 0; ni < 4; ++ni) {
            bfr[ni].v4[0] = *(const i32x4_t*)(Bbase + ni * 2048 + slo);
            bfr[ni].v4[1] = *(const i32x4_t*)(Bbase + ni * 2048 + shi);
        }
        #pragma unroll
        for (int mi = 0; mi < 4; ++mi) {
            Frag af;
            af.v4[0] = *(const i32x4_t*)(Abase + mi * 2048 + slo);
            af.v4[1] = *(const i32x4_t*)(Abase + mi * 2048 + shi);
            #pragma unroll
            for (int ni = 0; ni < 4; ++ni)
                acc[mi][ni] = __builtin_amdgcn_mfma_scale_f32_16x16x128_f8f6f4(
                    af.v8, bfr[ni].v8, acc[mi][ni],
                    0 /*cbsz: A=fp8 e4m3*/, 0 /*blgp: B=fp8 e4m3*/,
                    0, 127 /*scale A = 2^0*/, 0, 127 /*scale B = 2^0*/);
        }
    }

    // Epilogue: e = exp2(dot * iq_i * in_j); row-reduce; atomicAdd.
    // C/D layout (16x16): col = lane&15, row = quad*4 + reg.
    float inl[4];
    #pragma unroll
    for (int ni = 0; ni < 4; ++ni)
        inl[ni] = inx[j0 + wn * 64 + ni * 16 + lc];

    #pragma unroll
    for (int mi = 0; mi < 4; ++mi) {
        const int rbase = i0 + wm * 64 + mi * 16 + quad * 4;
        const float4 qv = *(const float4*)&iq[rbase];   // iq includes T^-1*log2e
        float qa[4] = {qv.x, qv.y, qv.z, qv.w};
        float rs[4] = {0.f, 0.f, 0.f, 0.f};
        #pragma unroll
        for (int ni = 0; ni < 4; ++ni) {
            #pragma unroll
            for (int r = 0; r < 4; ++r)
                rs[r] += __builtin_amdgcn_exp2f(acc[mi][ni][r] * qa[r] * inl[ni]);
        }
        #pragma unroll
        for (int m = 1; m < 16; m <<= 1) {
            #pragma unroll
            for (int r = 0; r < 4; ++r) rs[r] += __shfl_xor(rs[r], m, 64);
        }
        if (lc == 0) {
            #pragma unroll
            for (int r = 0; r < 4; ++r) atomicAdd(&rowsum[rbase + r], rs[r]);
        }
    }
}

// ---------------------------------------------------------------------------
// Kernel 3: loss = mean_b( log(s1+s2) - log(s1) ), s2 = rowsum/N.
// float4 loads, no division, fast log.
// ---------------------------------------------------------------------------
__global__ __launch_bounds__(256) void finalize_kernel(
    const float* __restrict__ s1, const float* __restrict__ rowsum,
    float* __restrict__ out, int B, float invN)
{
    __shared__ float red[4];
    const float4* s4 = (const float4*)s1;
    const float4* r4 = (const float4*)rowsum;
    float acc = 0.f;
    for (int i = threadIdx.x; i < B / 4; i += 256) {
        float4 a = s4[i];
        float4 s = r4[i];
        acc += __logf(a.x + s.x * invN) - __logf(a.x);
        acc += __logf(a.y + s.y * invN) - __logf(a.y);
        acc += __logf(a.z + s.z * invN) - __logf(a.z);
        acc += __logf(a.w + s.w * invN) - __logf(a.w);
    }
    #pragma unroll
    for (int off = 32; off > 0; off >>= 1) acc += __shfl_down(acc, off, 64);
    if ((threadIdx.x & 63) == 0) red[threadIdx.x >> 6] = acc;
    __syncthreads();
    if (threadIdx.x == 0)
        out[0] = (red[0] + red[1] + red[2] + red[3]) / (float)B;
}

extern "C" void kernel_launch(void* const* d_in, const int* in_sizes, int n_in,
                              void* d_out, int out_size, void* d_ws, size_t ws_size,
                              hipStream_t stream) {
    const float* q   = (const float*)d_in[0];
    const float* p   = (const float*)d_in[1];
    const float* neg = (const float*)d_in[2];
    const int B = in_sizes[0] / D;
    const int N = in_sizes[2] / D;

    char* ws = (char*)d_ws;
    uint8_t* Qb     = (uint8_t*)ws;
    uint8_t* Nb     = (uint8_t*)(ws + (size_t)B * D);
    float*   iq     = (float*)(ws + (size_t)(B + N) * D);
    float*   inx    = iq + B;
    float*   s1     = inx + N;
    float*   rowsum = s1 + B;

    prep_kernel<<<(B + N) / 4, 256, 0, stream>>>(q, p, neg, Qb, Nb, iq, inx, s1, rowsum, B);
    gemm_exp_rowsum<<<dim3(N / 128, B / 128), 256, 0, stream>>>(Qb, Nb, iq, inx, rowsum);
    finalize_kernel<<<1, 256, 0, stream>>>(s1, rowsum, (float*)d_out, B, 1.0f / (float)N);
}